// Round 1
// 292.020 us; speedup vs baseline: 1.0134x; 1.0134x over previous
//
#include <hip/hip_runtime.h>
#include <hip/hip_bf16.h>
#include <math.h>

// R11: qkv_rope epilogue de-transcendentalized. Theory: K-loop at m97-struct
// rate = ~59us of the 92us; the other ~33us is 4x powf + 20x sincosf + chained
// rotation per thread in the RoPE epilogue (VALUBusy~MfmaUtil~22%). Replace
// with precomputed interleaved (cos,sin) f32 table cs[2048][512] (8 MiB,
// generated inside cvt_all as grid-y==4; table is input-independent but ws is
// re-poisoned per launch so it is regenerated each call, ~3us).
// Also: softmax now skips reads beyond nvalid and writes beyond
// roundup(row+1,128) (pv never reads past its causal k-limit m0+128).
// Core GEMM unchanged: 128x128 tile, BK=32, global_load_lds width=16 into
// contiguous [128][32] LDS, slot c holds k-chunk c^((row>>1)&3); reads use
// quad^((row>>1)&3). mfma_f32_16x16x32_bf16, layouts verified (m89/m91).
// R9 lesson kept: no QKV fusion (224 VGPR + 32KB LDS -> 1 block/CU).

typedef __bf16 bf16x8 __attribute__((ext_vector_type(8)));
typedef float  f32x4  __attribute__((ext_vector_type(4)));

__device__ __forceinline__ ushort f2bf(float f) {
    __hip_bfloat16 h = __float2bfloat16(f);
    return *reinterpret_cast<ushort*>(&h);
}

__device__ __forceinline__ void async_load16(const ushort* g, ushort* l) {
    __builtin_amdgcn_global_load_lds(
        (const __attribute__((address_space(1))) void*)g,
        (__attribute__((address_space(3))) void*)l, 16, 0, 0);
}

// One launch for all 4 fp32->bf16 conversions + RoPE cos/sin table.
// grid (8192, 5): y<4 = conversions, y==4 = table gen (first 4096 x-blocks).
__global__ __launch_bounds__(256) void cvt_all_kernel(
    const float* __restrict__ x,  const float* __restrict__ wq,
    const float* __restrict__ wk, const float* __restrict__ wv,
    ushort* __restrict__ xb, ushort* __restrict__ wqb,
    ushort* __restrict__ wkb, ushort* __restrict__ wvb,
    float2* __restrict__ cs)
{
    const int t = blockIdx.y;
    if (t == 4) {
        // RoPE table: cs[pos*512 + i] = (cos(pos*phi_i), sin(pos*phi_i)),
        // phi_i = 10000^(-2*(i-1)/1024)  (reference's -1 quirk preserved).
        const int idx = blockIdx.x * 256 + threadIdx.x;
        if (idx < 2048 * 512) {
            const int pos = idx >> 9, i = idx & 511;
            const float phi = powf(10000.0f, -2.0f * ((float)i - 1.0f) / 1024.0f);
            float s, c;
            sincosf((float)pos * phi, &s, &c);
            cs[idx] = make_float2(c, s);
        }
        return;
    }
    const float* in  = (t == 0) ? x  : (t == 1) ? wq  : (t == 2) ? wk  : wv;
    ushort*      out = (t == 0) ? xb : (t == 1) ? wqb : (t == 2) ? wkb : wvb;
    const int n4 = (t == 0) ? 2097152 : 262144;
    int i = blockIdx.x * blockDim.x + threadIdx.x;
    if (i < n4) {
        float4 f = ((const float4*)in)[i];
        ushort4 o;
        o.x = f2bf(f.x); o.y = f2bf(f.y); o.z = f2bf(f.z); o.w = f2bf(f.w);
        ((ushort4*)out)[i] = o;
    }
}

// NT GEMM core, 128x128 tile, BK=32, bank-swizzled contiguous LDS [128][32].
__device__ __forceinline__ void gemm128_core(
    const ushort* __restrict__ A, const ushort* __restrict__ B,
    int lda, int ldb, int m0, int n0, int kIters,
    ushort* As, ushort* Bs, f32x4 acc[4][4])
{
    const int tid  = threadIdx.x;
    const int lane = tid & 63, wave = tid >> 6;
    const int wm = (wave >> 1) * 64, wn = (wave & 1) * 64;
    const int quad = lane >> 4, l16 = lane & 15;
    const int srow = lane >> 2, c = lane & 3;
    const int rr   = wave * 32 + srow;            // tile-relative staging row
    const int cc   = c ^ ((rr >> 1) & 3);         // swizzled source k-chunk
    const int scol = cc * 8;

    const ushort* ag0 = A + (size_t)(m0 + rr) * lda + scol;
    const ushort* bg0 = B + (size_t)(n0 + rr) * ldb + scol;
    const ushort* ag1 = ag0 + (size_t)16 * lda;   // row rr+16: same swizzle class
    const ushort* bg1 = bg0 + (size_t)16 * ldb;
    ushort* la0 = As + (wave * 32) * 32;
    ushort* la1 = la0 + 16 * 32;
    ushort* lb0 = Bs + (wave * 32) * 32;
    ushort* lb1 = lb0 + 16 * 32;

    for (int kt = 0; kt < kIters; ++kt) {
        const int k0 = kt * 32;
        async_load16(ag0 + k0, la0);
        async_load16(ag1 + k0, la1);
        async_load16(bg0 + k0, lb0);
        async_load16(bg1 + k0, lb1);
        __syncthreads();
        bf16x8 aF[4], bF[4];
#pragma unroll
        for (int i = 0; i < 4; ++i) {
            const int r = wm + i * 16 + l16;
            aF[i] = *(const bf16x8*)(As + r * 32 + ((quad ^ ((r >> 1) & 3)) * 8));
        }
#pragma unroll
        for (int j = 0; j < 4; ++j) {
            const int r = wn + j * 16 + l16;
            bF[j] = *(const bf16x8*)(Bs + r * 32 + ((quad ^ ((r >> 1) & 3)) * 8));
        }
#pragma unroll
        for (int i = 0; i < 4; ++i)
#pragma unroll
            for (int j = 0; j < 4; ++j)
                acc[i][j] = __builtin_amdgcn_mfma_f32_16x16x32_bf16(aF[i], bF[j], acc[i][j], 0, 0, 0);
        __syncthreads();
    }
}

#define ACC_INIT4(acc) \
    _Pragma("unroll") for (int i = 0; i < 4; ++i) \
    _Pragma("unroll") for (int j = 0; j < 4; ++j) \
    _Pragma("unroll") for (int r = 0; r < 4; ++r) acc[i][j][r] = 0.0f;

// QKV + RoPE, z-split. grid (64, 8, 3): m0 in [0,8192), n0 in [0,1024), z=Q/K/V.
__global__ __launch_bounds__(256) void qkv_rope_kernel(
    const ushort* __restrict__ xb, const ushort* __restrict__ wq,
    const ushort* __restrict__ wk, const ushort* __restrict__ wv,
    const float2* __restrict__ cs,
    ushort* __restrict__ Qr, ushort* __restrict__ Kr, ushort* __restrict__ VT)
{
    __shared__ __attribute__((aligned(16))) ushort As[128 * 32];
    __shared__ __attribute__((aligned(16))) ushort Bs[128 * 32];
    const int m0 = blockIdx.x * 128;
    const int n0 = blockIdx.y * 128;
    const int z  = blockIdx.z;
    const ushort* W = (z == 0) ? wq : (z == 1) ? wk : wv;

    f32x4 acc[4][4];
    ACC_INIT4(acc)
    gemm128_core(xb, W, 1024, 1024, m0, n0, 32, As, Bs, acc);

    const int lane = threadIdx.x & 63, wave = threadIdx.x >> 6;
    const int wm = (wave >> 1) * 64, wn = (wave & 1) * 64;
    const int quad = lane >> 4, l16 = lane & 15;

    if (z < 2) {
        ushort* out = (z == 0) ? Qr : Kr;
#pragma unroll
        for (int j = 0; j < 4; ++j) {
            const int n = n0 + wn + j * 16 + l16;
            const int iidx = n >> 1;
            const bool odd = n & 1;
#pragma unroll
            for (int i = 0; i < 4; ++i) {
                const int mbase = m0 + wm + i * 16 + quad * 4;
                const int pos0  = mbase & 2047;
                const float2* csp = cs + (size_t)pos0 * 512 + iidx;
#pragma unroll
                for (int r = 0; r < 4; ++r) {
                    const float2 sc = csp[(size_t)r * 512]; // (cos, sin) at pos0+r
                    float v = acc[i][j][r];
                    float p = __shfl_xor(v, 1);   // partner column n^1, same row
                    float o = odd ? (v * sc.x - p * sc.y) : (v * sc.x + p * sc.y);
                    out[(size_t)(mbase + r) * 1024 + n] = f2bf(o);
                }
            }
        }
    } else {
        // V transposed: VT[b][n][pos]; 4 consecutive pos per quad -> ushort4
#pragma unroll
        for (int i = 0; i < 4; ++i) {
            const int mbase = m0 + wm + i * 16 + quad * 4;
            const int b = mbase >> 11, pos0 = mbase & 2047;
#pragma unroll
            for (int j = 0; j < 4; ++j) {
                const int n = n0 + wn + j * 16 + l16;
                ushort4 o;
                o.x = f2bf(acc[i][j][0]); o.y = f2bf(acc[i][j][1]);
                o.z = f2bf(acc[i][j][2]); o.w = f2bf(acc[i][j][3]);
                *(ushort4*)(VT + ((size_t)b * 1024 + n) * 2048 + pos0) = o;
            }
        }
    }
}

// scores: grid (16, 16, 4); lower tiles only; S fp32 scaled 1/32.
__global__ __launch_bounds__(256) void scores_kernel(
    const ushort* __restrict__ Qr, const ushort* __restrict__ Kr,
    float* __restrict__ S)
{
    const int m0 = blockIdx.x * 128;
    const int n0 = blockIdx.y * 128;
    if (n0 > m0 + 127) return;
    const int b = blockIdx.z;
    __shared__ __attribute__((aligned(16))) ushort As[128 * 32];
    __shared__ __attribute__((aligned(16))) ushort Bs[128 * 32];
    const ushort* A = Qr + (size_t)b * 2048 * 1024;
    const ushort* B = Kr + (size_t)b * 2048 * 1024;
    float* Sb = S + (size_t)b * 2048 * 2048;

    f32x4 acc[4][4];
    ACC_INIT4(acc)
    gemm128_core(A, B, 1024, 1024, m0, n0, 32, As, Bs, acc);

    const int lane = threadIdx.x & 63, wave = threadIdx.x >> 6;
    const int wm = (wave >> 1) * 64, wn = (wave & 1) * 64;
    const int quad = lane >> 4, l16 = lane & 15;
#pragma unroll
    for (int i = 0; i < 4; ++i)
#pragma unroll
        for (int j = 0; j < 4; ++j) {
            const int n = n0 + wn + j * 16 + l16;
#pragma unroll
            for (int r = 0; r < 4; ++r) {
                const int m = m0 + wm + i * 16 + quad * 4 + r;
                Sb[(size_t)m * 2048 + n] = acc[i][j][r] * 0.03125f;
            }
        }
}

// Row softmax, register-staged: 8 elems/thread, one int4 bf16 write.
// R11: reads clipped to nvalid; writes clipped to roundup(row+1,128)
// (pv's causal k-limit guarantees it never reads past that).
__global__ __launch_bounds__(256) void softmax_kernel(
    const float* __restrict__ S, ushort* __restrict__ P)
{
    __shared__ float red[256];
    const int row = blockIdx.x, tid = threadIdx.x, b = blockIdx.y;
    const float* s = S + ((size_t)b * 2048 + row) * 2048;
    ushort*      p = P + ((size_t)b * 2048 + row) * 2048;
    const int nvalid = row + 1;
    const int wlimit = (row & ~127) + 128;
    const int j0 = tid * 8;

    float v[8] = {0.0f, 0.0f, 0.0f, 0.0f, 0.0f, 0.0f, 0.0f, 0.0f};
    if (j0 < nvalid) {
        float4 f0 = *(const float4*)(s + j0);
        v[0]=f0.x; v[1]=f0.y; v[2]=f0.z; v[3]=f0.w;
    }
    if (j0 + 4 < nvalid) {
        float4 f1 = *(const float4*)(s + j0 + 4);
        v[4]=f1.x; v[5]=f1.y; v[6]=f1.z; v[7]=f1.w;
    }

    float mx = -3.402823466e38f;
#pragma unroll
    for (int u = 0; u < 8; ++u) if (j0 + u < nvalid) mx = fmaxf(mx, v[u]);
    red[tid] = mx; __syncthreads();
    for (int off = 128; off > 0; off >>= 1) {
        if (tid < off) red[tid] = fmaxf(red[tid], red[tid + off]);
        __syncthreads();
    }
    mx = red[0]; __syncthreads();

    float sum = 0.0f;
#pragma unroll
    for (int u = 0; u < 8; ++u) {
        v[u] = (j0 + u < nvalid) ? __expf(v[u] - mx) : 0.0f;
        sum += v[u];
    }
    red[tid] = sum; __syncthreads();
    for (int off = 128; off > 0; off >>= 1) {
        if (tid < off) red[tid] += red[tid + off];
        __syncthreads();
    }
    const float inv = 1.0f / red[0];

    if (j0 < wlimit) {
        ushort o[8];
#pragma unroll
        for (int u = 0; u < 8; ++u) o[u] = f2bf(v[u] * inv);
        *(int4*)(p + j0) = *(const int4*)o;
    }
}

// pv: grid (16, 8, 4); causal k-limit.
__global__ __launch_bounds__(256) void pv_kernel(
    const ushort* __restrict__ P, const ushort* __restrict__ VT,
    float* __restrict__ out)
{
    __shared__ __attribute__((aligned(16))) ushort As[128 * 32];
    __shared__ __attribute__((aligned(16))) ushort Bs[128 * 32];
    const int m0 = blockIdx.x * 128;
    const int n0 = blockIdx.y * 128;
    const int b  = blockIdx.z;
    const ushort* A = P + (size_t)b * 2048 * 2048;
    const ushort* B = VT + (size_t)b * 1024 * 2048;
    const int kIters = (m0 + 128) / 32;   // causal: P[m][k]=0 for k>m

    f32x4 acc[4][4];
    ACC_INIT4(acc)
    gemm128_core(A, B, 2048, 2048, m0, n0, kIters, As, Bs, acc);

    const int lane = threadIdx.x & 63, wave = threadIdx.x >> 6;
    const int wm = (wave >> 1) * 64, wn = (wave & 1) * 64;
    const int quad = lane >> 4, l16 = lane & 15;
#pragma unroll
    for (int i = 0; i < 4; ++i)
#pragma unroll
        for (int j = 0; j < 4; ++j) {
            const int n = n0 + wn + j * 16 + l16;
#pragma unroll
            for (int r = 0; r < 4; ++r) {
                const int m = m0 + wm + i * 16 + quad * 4 + r;
                out[((size_t)b * 2048 + m) * 1024 + n] = acc[i][j][r];
            }
        }
}

extern "C" void kernel_launch(void* const* d_in, const int* in_sizes, int n_in,
                              void* d_out, int out_size, void* d_ws, size_t ws_size,
                              hipStream_t stream) {
    const float* x  = (const float*)d_in[0];
    const float* wq = (const float*)d_in[1];
    const float* wk = (const float*)d_in[2];
    const float* wv = (const float*)d_in[3];

    const size_t MiB = 1024 * 1024;
    char* ws = (char*)d_ws;
    ushort* xb  = (ushort*)(ws);              //  16 MiB [8192][1024] bf16
    ushort* wqb = (ushort*)(ws +  16 * MiB);  //   2 MiB
    ushort* wkb = (ushort*)(ws +  18 * MiB);  //   2 MiB
    ushort* wvb = (ushort*)(ws +  20 * MiB);  //   2 MiB
    ushort* Qr  = (ushort*)(ws +  22 * MiB);  //  16 MiB [4][2048][1024] bf16
    ushort* Kr  = (ushort*)(ws +  38 * MiB);  //  16 MiB
    ushort* VT  = (ushort*)(ws +  54 * MiB);  //  16 MiB [4][1024][2048] bf16
    float*  S   = (float* )(ws +  70 * MiB);  //  64 MiB [4][2048][2048] f32
    ushort* P   = (ushort*)(ws + 134 * MiB);  //  32 MiB [4][2048][2048] bf16
    float2* cs  = (float2*)(ws + 166 * MiB);  //   8 MiB [2048][512] (cos,sin) f32
    float*  out = (float*)d_out;              // ws use: 174 MiB (256 avail)

    cvt_all_kernel <<<dim3(8192, 5),   256, 0, stream>>>(x, wq, wk, wv, xb, wqb, wkb, wvb, cs);
    qkv_rope_kernel<<<dim3(64, 8, 3),  256, 0, stream>>>(xb, wqb, wkb, wvb, cs, Qr, Kr, VT);
    scores_kernel  <<<dim3(16, 16, 4), 256, 0, stream>>>(Qr, Kr, S);
    softmax_kernel <<<dim3(2048, 4),   256, 0, stream>>>(S, P);
    pv_kernel      <<<dim3(16, 8, 4),  256, 0, stream>>>(P, VT, out);
}

// Round 2
// 285.455 us; speedup vs baseline: 1.0367x; 1.0230x over previous
//
#include <hip/hip_runtime.h>
#include <hip/hip_bf16.h>
#include <math.h>

// R12: double-buffered 2-phase GEMM core (T3 minimum recipe). R11 post-mortem:
// qkv_rope MfmaUtil 24% == pure-MFMA-time/dur exactly -> latency/barrier-bound,
// not VALU (13.7%) and not HBM (20%). Old core issued global_load_lds
// immediately before the vmcnt(0)-draining __syncthreads -> full load latency
// exposed every K-step. New core: prologue-stage buf0; per iter: issue next
// k-tile into buf^1, ds_read+MFMA buf, one __syncthreads per tile (drains
// vmcnt for the prefetch after it had a whole compute phase in flight).
// Applies to qkv_rope, scores, pv via the shared core. LDS 16->32 KB/block
// (5 blocks/CU by LDS; VGPR ~100 -> not the limit).
// Kept from R11: cos/sin table (no epilogue trig), softmax read/write clip.
// Core layout unchanged: 128x128 tile, BK=32, width=16 global_load_lds into
// contiguous [128][32] LDS, slot c holds k-chunk c^((row>>1)&3); reads use
// quad^((row>>1)&3). mfma_f32_16x16x32_bf16 (layouts verified m89/m91).

typedef __bf16 bf16x8 __attribute__((ext_vector_type(8)));
typedef float  f32x4  __attribute__((ext_vector_type(4)));

__device__ __forceinline__ ushort f2bf(float f) {
    __hip_bfloat16 h = __float2bfloat16(f);
    return *reinterpret_cast<ushort*>(&h);
}

__device__ __forceinline__ void async_load16(const ushort* g, ushort* l) {
    __builtin_amdgcn_global_load_lds(
        (const __attribute__((address_space(1))) void*)g,
        (__attribute__((address_space(3))) void*)l, 16, 0, 0);
}

// One launch for all 4 fp32->bf16 conversions + RoPE cos/sin table.
// grid (8192, 5): y<4 = conversions, y==4 = table gen (first 4096 x-blocks).
__global__ __launch_bounds__(256) void cvt_all_kernel(
    const float* __restrict__ x,  const float* __restrict__ wq,
    const float* __restrict__ wk, const float* __restrict__ wv,
    ushort* __restrict__ xb, ushort* __restrict__ wqb,
    ushort* __restrict__ wkb, ushort* __restrict__ wvb,
    float2* __restrict__ cs)
{
    const int t = blockIdx.y;
    if (t == 4) {
        // RoPE table: cs[pos*512 + i] = (cos(pos*phi_i), sin(pos*phi_i)),
        // phi_i = 10000^(-2*(i-1)/1024)  (reference's -1 quirk preserved).
        const int idx = blockIdx.x * 256 + threadIdx.x;
        if (idx < 2048 * 512) {
            const int pos = idx >> 9, i = idx & 511;
            const float phi = powf(10000.0f, -2.0f * ((float)i - 1.0f) / 1024.0f);
            float s, c;
            sincosf((float)pos * phi, &s, &c);
            cs[idx] = make_float2(c, s);
        }
        return;
    }
    const float* in  = (t == 0) ? x  : (t == 1) ? wq  : (t == 2) ? wk  : wv;
    ushort*      out = (t == 0) ? xb : (t == 1) ? wqb : (t == 2) ? wkb : wvb;
    const int n4 = (t == 0) ? 2097152 : 262144;
    int i = blockIdx.x * blockDim.x + threadIdx.x;
    if (i < n4) {
        float4 f = ((const float4*)in)[i];
        ushort4 o;
        o.x = f2bf(f.x); o.y = f2bf(f.y); o.z = f2bf(f.z); o.w = f2bf(f.w);
        ((ushort4*)out)[i] = o;
    }
}

// NT GEMM core, 128x128 tile, BK=32, bank-swizzled contiguous LDS [128][32],
// 2-phase double-buffered: As/Bs are [2][128*32].
__device__ __forceinline__ void gemm128_core(
    const ushort* __restrict__ A, const ushort* __restrict__ B,
    int lda, int ldb, int m0, int n0, int kIters,
    ushort* As, ushort* Bs, f32x4 acc[4][4])
{
    const int tid  = threadIdx.x;
    const int lane = tid & 63, wave = tid >> 6;
    const int wm = (wave >> 1) * 64, wn = (wave & 1) * 64;
    const int quad = lane >> 4, l16 = lane & 15;
    const int srow = lane >> 2, c = lane & 3;
    const int rr   = wave * 32 + srow;            // tile-relative staging row
    const int cc   = c ^ ((rr >> 1) & 3);         // swizzled source k-chunk
    const int scol = cc * 8;

    const ushort* ag0 = A + (size_t)(m0 + rr) * lda + scol;
    const ushort* bg0 = B + (size_t)(n0 + rr) * ldb + scol;
    const ushort* ag1 = ag0 + (size_t)16 * lda;   // row rr+16: same swizzle class
    const ushort* bg1 = bg0 + (size_t)16 * ldb;
    const int lofs = (wave * 32) * 32;            // per-wave staging offset

    // Prologue: stage k-tile 0 into buffer 0; __syncthreads drains vmcnt(0).
    async_load16(ag0, As + lofs);
    async_load16(ag1, As + lofs + 16 * 32);
    async_load16(bg0, Bs + lofs);
    async_load16(bg1, Bs + lofs + 16 * 32);
    __syncthreads();

    int cur = 0;
    for (int kt = 0; kt < kIters; ++kt) {
        // Issue next k-tile into the other buffer BEFORE consuming current.
        // WAR-safe: buf^1 was last read before the previous barrier.
        if (kt + 1 < kIters) {
            const int k1 = (kt + 1) * 32;
            const int nb = (cur ^ 1) * 4096;
            async_load16(ag0 + k1, As + nb + lofs);
            async_load16(ag1 + k1, As + nb + lofs + 16 * 32);
            async_load16(bg0 + k1, Bs + nb + lofs);
            async_load16(bg1 + k1, Bs + nb + lofs + 16 * 32);
        }
        const ushort* as = As + cur * 4096;
        const ushort* bs = Bs + cur * 4096;
        bf16x8 aF[4], bF[4];
#pragma unroll
        for (int i = 0; i < 4; ++i) {
            const int r = wm + i * 16 + l16;
            aF[i] = *(const bf16x8*)(as + r * 32 + ((quad ^ ((r >> 1) & 3)) * 8));
        }
#pragma unroll
        for (int j = 0; j < 4; ++j) {
            const int r = wn + j * 16 + l16;
            bF[j] = *(const bf16x8*)(bs + r * 32 + ((quad ^ ((r >> 1) & 3)) * 8));
        }
#pragma unroll
        for (int i = 0; i < 4; ++i)
#pragma unroll
            for (int j = 0; j < 4; ++j)
                acc[i][j] = __builtin_amdgcn_mfma_f32_16x16x32_bf16(aF[i], bF[j], acc[i][j], 0, 0, 0);
        // Drains vmcnt(0) (prefetch had the whole compute phase in flight)
        // and lgkmcnt; next iteration reads buf^1.
        __syncthreads();
        cur ^= 1;
    }
}

#define ACC_INIT4(acc) \
    _Pragma("unroll") for (int i = 0; i < 4; ++i) \
    _Pragma("unroll") for (int j = 0; j < 4; ++j) \
    _Pragma("unroll") for (int r = 0; r < 4; ++r) acc[i][j][r] = 0.0f;

// QKV + RoPE, z-split. grid (64, 8, 3): m0 in [0,8192), n0 in [0,1024), z=Q/K/V.
__global__ __launch_bounds__(256) void qkv_rope_kernel(
    const ushort* __restrict__ xb, const ushort* __restrict__ wq,
    const ushort* __restrict__ wk, const ushort* __restrict__ wv,
    const float2* __restrict__ cs,
    ushort* __restrict__ Qr, ushort* __restrict__ Kr, ushort* __restrict__ VT)
{
    __shared__ __attribute__((aligned(16))) ushort As[2 * 128 * 32];
    __shared__ __attribute__((aligned(16))) ushort Bs[2 * 128 * 32];
    const int m0 = blockIdx.x * 128;
    const int n0 = blockIdx.y * 128;
    const int z  = blockIdx.z;
    const ushort* W = (z == 0) ? wq : (z == 1) ? wk : wv;

    f32x4 acc[4][4];
    ACC_INIT4(acc)
    gemm128_core(xb, W, 1024, 1024, m0, n0, 32, As, Bs, acc);

    const int lane = threadIdx.x & 63, wave = threadIdx.x >> 6;
    const int wm = (wave >> 1) * 64, wn = (wave & 1) * 64;
    const int quad = lane >> 4, l16 = lane & 15;

    if (z < 2) {
        ushort* out = (z == 0) ? Qr : Kr;
#pragma unroll
        for (int j = 0; j < 4; ++j) {
            const int n = n0 + wn + j * 16 + l16;
            const int iidx = n >> 1;
            const bool odd = n & 1;
#pragma unroll
            for (int i = 0; i < 4; ++i) {
                const int mbase = m0 + wm + i * 16 + quad * 4;
                const int pos0  = mbase & 2047;
                const float2* csp = cs + (size_t)pos0 * 512 + iidx;
#pragma unroll
                for (int r = 0; r < 4; ++r) {
                    const float2 sc = csp[(size_t)r * 512]; // (cos, sin) at pos0+r
                    float v = acc[i][j][r];
                    float p = __shfl_xor(v, 1);   // partner column n^1, same row
                    float o = odd ? (v * sc.x - p * sc.y) : (v * sc.x + p * sc.y);
                    out[(size_t)(mbase + r) * 1024 + n] = f2bf(o);
                }
            }
        }
    } else {
        // V transposed: VT[b][n][pos]; 4 consecutive pos per quad -> ushort4
#pragma unroll
        for (int i = 0; i < 4; ++i) {
            const int mbase = m0 + wm + i * 16 + quad * 4;
            const int b = mbase >> 11, pos0 = mbase & 2047;
#pragma unroll
            for (int j = 0; j < 4; ++j) {
                const int n = n0 + wn + j * 16 + l16;
                ushort4 o;
                o.x = f2bf(acc[i][j][0]); o.y = f2bf(acc[i][j][1]);
                o.z = f2bf(acc[i][j][2]); o.w = f2bf(acc[i][j][3]);
                *(ushort4*)(VT + ((size_t)b * 1024 + n) * 2048 + pos0) = o;
            }
        }
    }
}

// scores: grid (16, 16, 4); lower tiles only; S fp32 scaled 1/32.
__global__ __launch_bounds__(256) void scores_kernel(
    const ushort* __restrict__ Qr, const ushort* __restrict__ Kr,
    float* __restrict__ S)
{
    const int m0 = blockIdx.x * 128;
    const int n0 = blockIdx.y * 128;
    if (n0 > m0 + 127) return;
    const int b = blockIdx.z;
    __shared__ __attribute__((aligned(16))) ushort As[2 * 128 * 32];
    __shared__ __attribute__((aligned(16))) ushort Bs[2 * 128 * 32];
    const ushort* A = Qr + (size_t)b * 2048 * 1024;
    const ushort* B = Kr + (size_t)b * 2048 * 1024;
    float* Sb = S + (size_t)b * 2048 * 2048;

    f32x4 acc[4][4];
    ACC_INIT4(acc)
    gemm128_core(A, B, 1024, 1024, m0, n0, 32, As, Bs, acc);

    const int lane = threadIdx.x & 63, wave = threadIdx.x >> 6;
    const int wm = (wave >> 1) * 64, wn = (wave & 1) * 64;
    const int quad = lane >> 4, l16 = lane & 15;
#pragma unroll
    for (int i = 0; i < 4; ++i)
#pragma unroll
        for (int j = 0; j < 4; ++j) {
            const int n = n0 + wn + j * 16 + l16;
#pragma unroll
            for (int r = 0; r < 4; ++r) {
                const int m = m0 + wm + i * 16 + quad * 4 + r;
                Sb[(size_t)m * 2048 + n] = acc[i][j][r] * 0.03125f;
            }
        }
}

// Row softmax, register-staged: 8 elems/thread, one int4 bf16 write.
// Reads clipped to nvalid; writes clipped to roundup(row+1,128)
// (pv's causal k-limit guarantees it never reads past that).
__global__ __launch_bounds__(256) void softmax_kernel(
    const float* __restrict__ S, ushort* __restrict__ P)
{
    __shared__ float red[256];
    const int row = blockIdx.x, tid = threadIdx.x, b = blockIdx.y;
    const float* s = S + ((size_t)b * 2048 + row) * 2048;
    ushort*      p = P + ((size_t)b * 2048 + row) * 2048;
    const int nvalid = row + 1;
    const int wlimit = (row & ~127) + 128;
    const int j0 = tid * 8;

    float v[8] = {0.0f, 0.0f, 0.0f, 0.0f, 0.0f, 0.0f, 0.0f, 0.0f};
    if (j0 < nvalid) {
        float4 f0 = *(const float4*)(s + j0);
        v[0]=f0.x; v[1]=f0.y; v[2]=f0.z; v[3]=f0.w;
    }
    if (j0 + 4 < nvalid) {
        float4 f1 = *(const float4*)(s + j0 + 4);
        v[4]=f1.x; v[5]=f1.y; v[6]=f1.z; v[7]=f1.w;
    }

    float mx = -3.402823466e38f;
#pragma unroll
    for (int u = 0; u < 8; ++u) if (j0 + u < nvalid) mx = fmaxf(mx, v[u]);
    red[tid] = mx; __syncthreads();
    for (int off = 128; off > 0; off >>= 1) {
        if (tid < off) red[tid] = fmaxf(red[tid], red[tid + off]);
        __syncthreads();
    }
    mx = red[0]; __syncthreads();

    float sum = 0.0f;
#pragma unroll
    for (int u = 0; u < 8; ++u) {
        v[u] = (j0 + u < nvalid) ? __expf(v[u] - mx) : 0.0f;
        sum += v[u];
    }
    red[tid] = sum; __syncthreads();
    for (int off = 128; off > 0; off >>= 1) {
        if (tid < off) red[tid] += red[tid + off];
        __syncthreads();
    }
    const float inv = 1.0f / red[0];

    if (j0 < wlimit) {
        ushort o[8];
#pragma unroll
        for (int u = 0; u < 8; ++u) o[u] = f2bf(v[u] * inv);
        *(int4*)(p + j0) = *(const int4*)o;
    }
}

// pv: grid (16, 8, 4); causal k-limit.
__global__ __launch_bounds__(256) void pv_kernel(
    const ushort* __restrict__ P, const ushort* __restrict__ VT,
    float* __restrict__ out)
{
    __shared__ __attribute__((aligned(16))) ushort As[2 * 128 * 32];
    __shared__ __attribute__((aligned(16))) ushort Bs[2 * 128 * 32];
    const int m0 = blockIdx.x * 128;
    const int n0 = blockIdx.y * 128;
    const int b  = blockIdx.z;
    const ushort* A = P + (size_t)b * 2048 * 2048;
    const ushort* B = VT + (size_t)b * 1024 * 2048;
    const int kIters = (m0 + 128) / 32;   // causal: P[m][k]=0 for k>m

    f32x4 acc[4][4];
    ACC_INIT4(acc)
    gemm128_core(A, B, 2048, 2048, m0, n0, kIters, As, Bs, acc);

    const int lane = threadIdx.x & 63, wave = threadIdx.x >> 6;
    const int wm = (wave >> 1) * 64, wn = (wave & 1) * 64;
    const int quad = lane >> 4, l16 = lane & 15;
#pragma unroll
    for (int i = 0; i < 4; ++i)
#pragma unroll
        for (int j = 0; j < 4; ++j) {
            const int n = n0 + wn + j * 16 + l16;
#pragma unroll
            for (int r = 0; r < 4; ++r) {
                const int m = m0 + wm + i * 16 + quad * 4 + r;
                out[((size_t)b * 2048 + m) * 1024 + n] = acc[i][j][r];
            }
        }
}

extern "C" void kernel_launch(void* const* d_in, const int* in_sizes, int n_in,
                              void* d_out, int out_size, void* d_ws, size_t ws_size,
                              hipStream_t stream) {
    const float* x  = (const float*)d_in[0];
    const float* wq = (const float*)d_in[1];
    const float* wk = (const float*)d_in[2];
    const float* wv = (const float*)d_in[3];

    const size_t MiB = 1024 * 1024;
    char* ws = (char*)d_ws;
    ushort* xb  = (ushort*)(ws);              //  16 MiB [8192][1024] bf16
    ushort* wqb = (ushort*)(ws +  16 * MiB);  //   2 MiB
    ushort* wkb = (ushort*)(ws +  18 * MiB);  //   2 MiB
    ushort* wvb = (ushort*)(ws +  20 * MiB);  //   2 MiB
    ushort* Qr  = (ushort*)(ws +  22 * MiB);  //  16 MiB [4][2048][1024] bf16
    ushort* Kr  = (ushort*)(ws +  38 * MiB);  //  16 MiB
    ushort* VT  = (ushort*)(ws +  54 * MiB);  //  16 MiB [4][1024][2048] bf16
    float*  S   = (float* )(ws +  70 * MiB);  //  64 MiB [4][2048][2048] f32
    ushort* P   = (ushort*)(ws + 134 * MiB);  //  32 MiB [4][2048][2048] bf16
    float2* cs  = (float2*)(ws + 166 * MiB);  //   8 MiB [2048][512] (cos,sin) f32
    float*  out = (float*)d_out;              // ws use: 174 MiB (256 avail)

    cvt_all_kernel <<<dim3(8192, 5),   256, 0, stream>>>(x, wq, wk, wv, xb, wqb, wkb, wvb, cs);
    qkv_rope_kernel<<<dim3(64, 8, 3),  256, 0, stream>>>(xb, wqb, wkb, wvb, cs, Qr, Kr, VT);
    scores_kernel  <<<dim3(16, 16, 4), 256, 0, stream>>>(Qr, Kr, S);
    softmax_kernel <<<dim3(2048, 4),   256, 0, stream>>>(S, P);
    pv_kernel      <<<dim3(16, 8, 4),  256, 0, stream>>>(P, VT, out);
}

// Round 3
// 275.263 us; speedup vs baseline: 1.0750x; 1.0370x over previous
//
#include <hip/hip_runtime.h>
#include <hip/hip_bf16.h>
#include <math.h>

// R13: per-kernel core selection. R12 post-mortem: dbuf core HURT qkv_rope
// (1536 blocks, 5-6 resident/CU -> implicit wave overlap already hid latency;
// dbuf's extra VALU (14->35%) was pure critical-path cost) but HELPED
// scores/pv (~2 blocks/CU, no inter-block overlap; -19us combined).
// So: qkv_rope uses the R11 single-buffer core; scores/pv keep the R12
// double-buffered core. Plus: pv m-tile interleave (0,15,1,14,...) to mix
// heavy (kIters=64) and light (kIters=4) blocks across scheduling rounds.
// Kept: cos/sin table (no epilogue trig), softmax read/write clip.
// Core layout: 128x128 tile, BK=32, width=16 global_load_lds into contiguous
// [128][32] LDS, slot c holds k-chunk c^((row>>1)&3); reads use
// quad^((row>>1)&3). mfma_f32_16x16x32_bf16 (layouts verified m89/m91).

typedef __bf16 bf16x8 __attribute__((ext_vector_type(8)));
typedef float  f32x4  __attribute__((ext_vector_type(4)));

__device__ __forceinline__ ushort f2bf(float f) {
    __hip_bfloat16 h = __float2bfloat16(f);
    return *reinterpret_cast<ushort*>(&h);
}

__device__ __forceinline__ void async_load16(const ushort* g, ushort* l) {
    __builtin_amdgcn_global_load_lds(
        (const __attribute__((address_space(1))) void*)g,
        (__attribute__((address_space(3))) void*)l, 16, 0, 0);
}

// One launch for all 4 fp32->bf16 conversions + RoPE cos/sin table.
// grid (8192, 5): y<4 = conversions, y==4 = table gen (first 4096 x-blocks).
__global__ __launch_bounds__(256) void cvt_all_kernel(
    const float* __restrict__ x,  const float* __restrict__ wq,
    const float* __restrict__ wk, const float* __restrict__ wv,
    ushort* __restrict__ xb, ushort* __restrict__ wqb,
    ushort* __restrict__ wkb, ushort* __restrict__ wvb,
    float2* __restrict__ cs)
{
    const int t = blockIdx.y;
    if (t == 4) {
        // RoPE table: cs[pos*512 + i] = (cos(pos*phi_i), sin(pos*phi_i)),
        // phi_i = 10000^(-2*(i-1)/1024)  (reference's -1 quirk preserved).
        const int idx = blockIdx.x * 256 + threadIdx.x;
        if (idx < 2048 * 512) {
            const int pos = idx >> 9, i = idx & 511;
            const float phi = powf(10000.0f, -2.0f * ((float)i - 1.0f) / 1024.0f);
            float s, c;
            sincosf((float)pos * phi, &s, &c);
            cs[idx] = make_float2(c, s);
        }
        return;
    }
    const float* in  = (t == 0) ? x  : (t == 1) ? wq  : (t == 2) ? wk  : wv;
    ushort*      out = (t == 0) ? xb : (t == 1) ? wqb : (t == 2) ? wkb : wvb;
    const int n4 = (t == 0) ? 2097152 : 262144;
    int i = blockIdx.x * blockDim.x + threadIdx.x;
    if (i < n4) {
        float4 f = ((const float4*)in)[i];
        ushort4 o;
        o.x = f2bf(f.x); o.y = f2bf(f.y); o.z = f2bf(f.z); o.w = f2bf(f.w);
        ((ushort4*)out)[i] = o;
    }
}

// ---------------- single-buffer core (R11): for high-occupancy kernels ----
__device__ __forceinline__ void gemm128_core_sb(
    const ushort* __restrict__ A, const ushort* __restrict__ B,
    int lda, int ldb, int m0, int n0, int kIters,
    ushort* As, ushort* Bs, f32x4 acc[4][4])
{
    const int tid  = threadIdx.x;
    const int lane = tid & 63, wave = tid >> 6;
    const int wm = (wave >> 1) * 64, wn = (wave & 1) * 64;
    const int quad = lane >> 4, l16 = lane & 15;
    const int srow = lane >> 2, c = lane & 3;
    const int rr   = wave * 32 + srow;
    const int cc   = c ^ ((rr >> 1) & 3);
    const int scol = cc * 8;

    const ushort* ag0 = A + (size_t)(m0 + rr) * lda + scol;
    const ushort* bg0 = B + (size_t)(n0 + rr) * ldb + scol;
    const ushort* ag1 = ag0 + (size_t)16 * lda;
    const ushort* bg1 = bg0 + (size_t)16 * ldb;
    ushort* la0 = As + (wave * 32) * 32;
    ushort* la1 = la0 + 16 * 32;
    ushort* lb0 = Bs + (wave * 32) * 32;
    ushort* lb1 = lb0 + 16 * 32;

    for (int kt = 0; kt < kIters; ++kt) {
        const int k0 = kt * 32;
        async_load16(ag0 + k0, la0);
        async_load16(ag1 + k0, la1);
        async_load16(bg0 + k0, lb0);
        async_load16(bg1 + k0, lb1);
        __syncthreads();
        bf16x8 aF[4], bF[4];
#pragma unroll
        for (int i = 0; i < 4; ++i) {
            const int r = wm + i * 16 + l16;
            aF[i] = *(const bf16x8*)(As + r * 32 + ((quad ^ ((r >> 1) & 3)) * 8));
        }
#pragma unroll
        for (int j = 0; j < 4; ++j) {
            const int r = wn + j * 16 + l16;
            bF[j] = *(const bf16x8*)(Bs + r * 32 + ((quad ^ ((r >> 1) & 3)) * 8));
        }
#pragma unroll
        for (int i = 0; i < 4; ++i)
#pragma unroll
            for (int j = 0; j < 4; ++j)
                acc[i][j] = __builtin_amdgcn_mfma_f32_16x16x32_bf16(aF[i], bF[j], acc[i][j], 0, 0, 0);
        __syncthreads();
    }
}

// ---------------- double-buffered core (R12): for low-occupancy kernels ---
__device__ __forceinline__ void gemm128_core_db(
    const ushort* __restrict__ A, const ushort* __restrict__ B,
    int lda, int ldb, int m0, int n0, int kIters,
    ushort* As, ushort* Bs, f32x4 acc[4][4])
{
    const int tid  = threadIdx.x;
    const int lane = tid & 63, wave = tid >> 6;
    const int wm = (wave >> 1) * 64, wn = (wave & 1) * 64;
    const int quad = lane >> 4, l16 = lane & 15;
    const int srow = lane >> 2, c = lane & 3;
    const int rr   = wave * 32 + srow;
    const int cc   = c ^ ((rr >> 1) & 3);
    const int scol = cc * 8;

    const ushort* ag0 = A + (size_t)(m0 + rr) * lda + scol;
    const ushort* bg0 = B + (size_t)(n0 + rr) * ldb + scol;
    const ushort* ag1 = ag0 + (size_t)16 * lda;
    const ushort* bg1 = bg0 + (size_t)16 * ldb;
    const int lofs = (wave * 32) * 32;

    // Prologue: stage k-tile 0 into buffer 0.
    async_load16(ag0, As + lofs);
    async_load16(ag1, As + lofs + 16 * 32);
    async_load16(bg0, Bs + lofs);
    async_load16(bg1, Bs + lofs + 16 * 32);
    __syncthreads();

    int cur = 0;
    for (int kt = 0; kt < kIters; ++kt) {
        if (kt + 1 < kIters) {
            const int k1 = (kt + 1) * 32;
            const int nb = (cur ^ 1) * 4096;
            async_load16(ag0 + k1, As + nb + lofs);
            async_load16(ag1 + k1, As + nb + lofs + 16 * 32);
            async_load16(bg0 + k1, Bs + nb + lofs);
            async_load16(bg1 + k1, Bs + nb + lofs + 16 * 32);
        }
        const ushort* as = As + cur * 4096;
        const ushort* bs = Bs + cur * 4096;
        bf16x8 aF[4], bF[4];
#pragma unroll
        for (int i = 0; i < 4; ++i) {
            const int r = wm + i * 16 + l16;
            aF[i] = *(const bf16x8*)(as + r * 32 + ((quad ^ ((r >> 1) & 3)) * 8));
        }
#pragma unroll
        for (int j = 0; j < 4; ++j) {
            const int r = wn + j * 16 + l16;
            bF[j] = *(const bf16x8*)(bs + r * 32 + ((quad ^ ((r >> 1) & 3)) * 8));
        }
#pragma unroll
        for (int i = 0; i < 4; ++i)
#pragma unroll
            for (int j = 0; j < 4; ++j)
                acc[i][j] = __builtin_amdgcn_mfma_f32_16x16x32_bf16(aF[i], bF[j], acc[i][j], 0, 0, 0);
        __syncthreads();
        cur ^= 1;
    }
}

#define ACC_INIT4(acc) \
    _Pragma("unroll") for (int i = 0; i < 4; ++i) \
    _Pragma("unroll") for (int j = 0; j < 4; ++j) \
    _Pragma("unroll") for (int r = 0; r < 4; ++r) acc[i][j][r] = 0.0f;

// QKV + RoPE, z-split. grid (64, 8, 3). Single-buffer core (5-6 blocks/CU).
__global__ __launch_bounds__(256) void qkv_rope_kernel(
    const ushort* __restrict__ xb, const ushort* __restrict__ wq,
    const ushort* __restrict__ wk, const ushort* __restrict__ wv,
    const float2* __restrict__ cs,
    ushort* __restrict__ Qr, ushort* __restrict__ Kr, ushort* __restrict__ VT)
{
    __shared__ __attribute__((aligned(16))) ushort As[128 * 32];
    __shared__ __attribute__((aligned(16))) ushort Bs[128 * 32];
    const int m0 = blockIdx.x * 128;
    const int n0 = blockIdx.y * 128;
    const int z  = blockIdx.z;
    const ushort* W = (z == 0) ? wq : (z == 1) ? wk : wv;

    f32x4 acc[4][4];
    ACC_INIT4(acc)
    gemm128_core_sb(xb, W, 1024, 1024, m0, n0, 32, As, Bs, acc);

    const int lane = threadIdx.x & 63, wave = threadIdx.x >> 6;
    const int wm = (wave >> 1) * 64, wn = (wave & 1) * 64;
    const int quad = lane >> 4, l16 = lane & 15;

    if (z < 2) {
        ushort* out = (z == 0) ? Qr : Kr;
#pragma unroll
        for (int j = 0; j < 4; ++j) {
            const int n = n0 + wn + j * 16 + l16;
            const int iidx = n >> 1;
            const bool odd = n & 1;
#pragma unroll
            for (int i = 0; i < 4; ++i) {
                const int mbase = m0 + wm + i * 16 + quad * 4;
                const int pos0  = mbase & 2047;
                const float2* csp = cs + (size_t)pos0 * 512 + iidx;
#pragma unroll
                for (int r = 0; r < 4; ++r) {
                    const float2 sc = csp[(size_t)r * 512]; // (cos, sin) at pos0+r
                    float v = acc[i][j][r];
                    float p = __shfl_xor(v, 1);   // partner column n^1, same row
                    float o = odd ? (v * sc.x - p * sc.y) : (v * sc.x + p * sc.y);
                    out[(size_t)(mbase + r) * 1024 + n] = f2bf(o);
                }
            }
        }
    } else {
        // V transposed: VT[b][n][pos]; 4 consecutive pos per quad -> ushort4
#pragma unroll
        for (int i = 0; i < 4; ++i) {
            const int mbase = m0 + wm + i * 16 + quad * 4;
            const int b = mbase >> 11, pos0 = mbase & 2047;
#pragma unroll
            for (int j = 0; j < 4; ++j) {
                const int n = n0 + wn + j * 16 + l16;
                ushort4 o;
                o.x = f2bf(acc[i][j][0]); o.y = f2bf(acc[i][j][1]);
                o.z = f2bf(acc[i][j][2]); o.w = f2bf(acc[i][j][3]);
                *(ushort4*)(VT + ((size_t)b * 1024 + n) * 2048 + pos0) = o;
            }
        }
    }
}

// scores: grid (16, 16, 4); lower tiles only; S fp32 scaled 1/32. Dbuf core.
__global__ __launch_bounds__(256) void scores_kernel(
    const ushort* __restrict__ Qr, const ushort* __restrict__ Kr,
    float* __restrict__ S)
{
    const int m0 = blockIdx.x * 128;
    const int n0 = blockIdx.y * 128;
    if (n0 > m0 + 127) return;
    const int b = blockIdx.z;
    __shared__ __attribute__((aligned(16))) ushort As[2 * 128 * 32];
    __shared__ __attribute__((aligned(16))) ushort Bs[2 * 128 * 32];
    const ushort* A = Qr + (size_t)b * 2048 * 1024;
    const ushort* B = Kr + (size_t)b * 2048 * 1024;
    float* Sb = S + (size_t)b * 2048 * 2048;

    f32x4 acc[4][4];
    ACC_INIT4(acc)
    gemm128_core_db(A, B, 1024, 1024, m0, n0, 32, As, Bs, acc);

    const int lane = threadIdx.x & 63, wave = threadIdx.x >> 6;
    const int wm = (wave >> 1) * 64, wn = (wave & 1) * 64;
    const int quad = lane >> 4, l16 = lane & 15;
#pragma unroll
    for (int i = 0; i < 4; ++i)
#pragma unroll
        for (int j = 0; j < 4; ++j) {
            const int n = n0 + wn + j * 16 + l16;
#pragma unroll
            for (int r = 0; r < 4; ++r) {
                const int m = m0 + wm + i * 16 + quad * 4 + r;
                Sb[(size_t)m * 2048 + n] = acc[i][j][r] * 0.03125f;
            }
        }
}

// Row softmax, register-staged: 8 elems/thread, one int4 bf16 write.
// Reads clipped to nvalid; writes clipped to roundup(row+1,128).
__global__ __launch_bounds__(256) void softmax_kernel(
    const float* __restrict__ S, ushort* __restrict__ P)
{
    __shared__ float red[256];
    const int row = blockIdx.x, tid = threadIdx.x, b = blockIdx.y;
    const float* s = S + ((size_t)b * 2048 + row) * 2048;
    ushort*      p = P + ((size_t)b * 2048 + row) * 2048;
    const int nvalid = row + 1;
    const int wlimit = (row & ~127) + 128;
    const int j0 = tid * 8;

    float v[8] = {0.0f, 0.0f, 0.0f, 0.0f, 0.0f, 0.0f, 0.0f, 0.0f};
    if (j0 < nvalid) {
        float4 f0 = *(const float4*)(s + j0);
        v[0]=f0.x; v[1]=f0.y; v[2]=f0.z; v[3]=f0.w;
    }
    if (j0 + 4 < nvalid) {
        float4 f1 = *(const float4*)(s + j0 + 4);
        v[4]=f1.x; v[5]=f1.y; v[6]=f1.z; v[7]=f1.w;
    }

    float mx = -3.402823466e38f;
#pragma unroll
    for (int u = 0; u < 8; ++u) if (j0 + u < nvalid) mx = fmaxf(mx, v[u]);
    red[tid] = mx; __syncthreads();
    for (int off = 128; off > 0; off >>= 1) {
        if (tid < off) red[tid] = fmaxf(red[tid], red[tid + off]);
        __syncthreads();
    }
    mx = red[0]; __syncthreads();

    float sum = 0.0f;
#pragma unroll
    for (int u = 0; u < 8; ++u) {
        v[u] = (j0 + u < nvalid) ? __expf(v[u] - mx) : 0.0f;
        sum += v[u];
    }
    red[tid] = sum; __syncthreads();
    for (int off = 128; off > 0; off >>= 1) {
        if (tid < off) red[tid] += red[tid + off];
        __syncthreads();
    }
    const float inv = 1.0f / red[0];

    if (j0 < wlimit) {
        ushort o[8];
#pragma unroll
        for (int u = 0; u < 8; ++u) o[u] = f2bf(v[u] * inv);
        *(int4*)(p + j0) = *(const int4*)o;
    }
}

// pv: grid (16, 8, 4); causal k-limit; dbuf core; m-tile interleave for
// K-balance (kIters 4..64 -> pair heavy with light in dispatch order).
__global__ __launch_bounds__(256) void pv_kernel(
    const ushort* __restrict__ P, const ushort* __restrict__ VT,
    float* __restrict__ out)
{
    __shared__ __attribute__((aligned(16))) ushort As[2 * 128 * 32];
    __shared__ __attribute__((aligned(16))) ushort Bs[2 * 128 * 32];
    const int x  = blockIdx.x;
    const int mt = (x & 1) ? (15 - (x >> 1)) : (x >> 1);  // 0,15,1,14,...
    const int m0 = mt * 128;
    const int n0 = blockIdx.y * 128;
    const int b  = blockIdx.z;
    const ushort* A = P + (size_t)b * 2048 * 2048;
    const ushort* B = VT + (size_t)b * 1024 * 2048;
    const int kIters = (m0 + 128) / 32;   // causal: P[m][k]=0 for k>m

    f32x4 acc[4][4];
    ACC_INIT4(acc)
    gemm128_core_db(A, B, 2048, 2048, m0, n0, kIters, As, Bs, acc);

    const int lane = threadIdx.x & 63, wave = threadIdx.x >> 6;
    const int wm = (wave >> 1) * 64, wn = (wave & 1) * 64;
    const int quad = lane >> 4, l16 = lane & 15;
#pragma unroll
    for (int i = 0; i < 4; ++i)
#pragma unroll
        for (int j = 0; j < 4; ++j) {
            const int n = n0 + wn + j * 16 + l16;
#pragma unroll
            for (int r = 0; r < 4; ++r) {
                const int m = m0 + wm + i * 16 + quad * 4 + r;
                out[((size_t)b * 2048 + m) * 1024 + n] = acc[i][j][r];
            }
        }
}

extern "C" void kernel_launch(void* const* d_in, const int* in_sizes, int n_in,
                              void* d_out, int out_size, void* d_ws, size_t ws_size,
                              hipStream_t stream) {
    const float* x  = (const float*)d_in[0];
    const float* wq = (const float*)d_in[1];
    const float* wk = (const float*)d_in[2];
    const float* wv = (const float*)d_in[3];

    const size_t MiB = 1024 * 1024;
    char* ws = (char*)d_ws;
    ushort* xb  = (ushort*)(ws);              //  16 MiB [8192][1024] bf16
    ushort* wqb = (ushort*)(ws +  16 * MiB);  //   2 MiB
    ushort* wkb = (ushort*)(ws +  18 * MiB);  //   2 MiB
    ushort* wvb = (ushort*)(ws +  20 * MiB);  //   2 MiB
    ushort* Qr  = (ushort*)(ws +  22 * MiB);  //  16 MiB [4][2048][1024] bf16
    ushort* Kr  = (ushort*)(ws +  38 * MiB);  //  16 MiB
    ushort* VT  = (ushort*)(ws +  54 * MiB);  //  16 MiB [4][1024][2048] bf16
    float*  S   = (float* )(ws +  70 * MiB);  //  64 MiB [4][2048][2048] f32
    ushort* P   = (ushort*)(ws + 134 * MiB);  //  32 MiB [4][2048][2048] bf16
    float2* cs  = (float2*)(ws + 166 * MiB);  //   8 MiB [2048][512] (cos,sin) f32
    float*  out = (float*)d_out;              // ws use: 174 MiB (256 avail)

    cvt_all_kernel <<<dim3(8192, 5),   256, 0, stream>>>(x, wq, wk, wv, xb, wqb, wkb, wvb, cs);
    qkv_rope_kernel<<<dim3(64, 8, 3),  256, 0, stream>>>(xb, wqb, wkb, wvb, cs, Qr, Kr, VT);
    scores_kernel  <<<dim3(16, 16, 4), 256, 0, stream>>>(Qr, Kr, S);
    softmax_kernel <<<dim3(2048, 4),   256, 0, stream>>>(S, P);
    pv_kernel      <<<dim3(16, 8, 4),  256, 0, stream>>>(P, VT, out);
}

// Round 4
// 271.629 us; speedup vs baseline: 1.0894x; 1.0134x over previous
//
#include <hip/hip_runtime.h>
#include <hip/hip_bf16.h>
#include <math.h>

// R14: counted-vmcnt ring core (T4) for scores/pv. R13 post-mortem: qkv's
// R11-85.5 vs R13-98.4 on identical code = cross-run noise (rule #13);
// real budget: qkv ~98, scores+pv ~130us @ ~280 GF/s (2.1 blocks/CU,
// latency-naked). The db core's __syncthreads forces vmcnt(0) every K-step,
// draining the just-issued prefetch (compute ~400cyc < HBM ~900cyc -> ~500cyc
// exposed/iter). New core: 3-buffer LDS ring (48KB, 3 blocks/CU), TWO
// prefetches in flight, ONE raw s_barrier + s_waitcnt vmcnt(4) per K-step
// (never 0 in steady state). WAR: STAGE(kt+2) issued after the barrier that
// postdates all reads of its target buffer (read in iter kt-1). RAW:
// vmcnt(4)=own P(kt) done, barrier=everyone's. vmcnt retires in issue order
// (m135). qkv keeps sb core (ring would cut its occupancy 5->3 blocks/CU;
// that A/B is a future round). Kept: cos/sin table, softmax clip, pv
// m-interleave. Layout: 128x128 tile, BK=32, width=16 global_load_lds into
// contiguous [128][32] LDS, slot c holds k-chunk c^((row>>1)&3); reads use
// quad^((row>>1)&3). mfma_f32_16x16x32_bf16 (layouts verified m89/m91).

typedef __bf16 bf16x8 __attribute__((ext_vector_type(8)));
typedef float  f32x4  __attribute__((ext_vector_type(4)));

__device__ __forceinline__ ushort f2bf(float f) {
    __hip_bfloat16 h = __float2bfloat16(f);
    return *reinterpret_cast<ushort*>(&h);
}

__device__ __forceinline__ void async_load16(const ushort* g, ushort* l) {
    __builtin_amdgcn_global_load_lds(
        (const __attribute__((address_space(1))) void*)g,
        (__attribute__((address_space(3))) void*)l, 16, 0, 0);
}

// One launch for all 4 fp32->bf16 conversions + RoPE cos/sin table.
// grid (8192, 5): y<4 = conversions, y==4 = table gen (first 4096 x-blocks).
__global__ __launch_bounds__(256) void cvt_all_kernel(
    const float* __restrict__ x,  const float* __restrict__ wq,
    const float* __restrict__ wk, const float* __restrict__ wv,
    ushort* __restrict__ xb, ushort* __restrict__ wqb,
    ushort* __restrict__ wkb, ushort* __restrict__ wvb,
    float2* __restrict__ cs)
{
    const int t = blockIdx.y;
    if (t == 4) {
        // RoPE table: cs[pos*512 + i] = (cos(pos*phi_i), sin(pos*phi_i)),
        // phi_i = 10000^(-2*(i-1)/1024)  (reference's -1 quirk preserved).
        const int idx = blockIdx.x * 256 + threadIdx.x;
        if (idx < 2048 * 512) {
            const int pos = idx >> 9, i = idx & 511;
            const float phi = powf(10000.0f, -2.0f * ((float)i - 1.0f) / 1024.0f);
            float s, c;
            sincosf((float)pos * phi, &s, &c);
            cs[idx] = make_float2(c, s);
        }
        return;
    }
    const float* in  = (t == 0) ? x  : (t == 1) ? wq  : (t == 2) ? wk  : wv;
    ushort*      out = (t == 0) ? xb : (t == 1) ? wqb : (t == 2) ? wkb : wvb;
    const int n4 = (t == 0) ? 2097152 : 262144;
    int i = blockIdx.x * blockDim.x + threadIdx.x;
    if (i < n4) {
        float4 f = ((const float4*)in)[i];
        ushort4 o;
        o.x = f2bf(f.x); o.y = f2bf(f.y); o.z = f2bf(f.z); o.w = f2bf(f.w);
        ((ushort4*)out)[i] = o;
    }
}

// ---------------- single-buffer core (R11): for high-occupancy kernels ----
__device__ __forceinline__ void gemm128_core_sb(
    const ushort* __restrict__ A, const ushort* __restrict__ B,
    int lda, int ldb, int m0, int n0, int kIters,
    ushort* As, ushort* Bs, f32x4 acc[4][4])
{
    const int tid  = threadIdx.x;
    const int lane = tid & 63, wave = tid >> 6;
    const int wm = (wave >> 1) * 64, wn = (wave & 1) * 64;
    const int quad = lane >> 4, l16 = lane & 15;
    const int srow = lane >> 2, c = lane & 3;
    const int rr   = wave * 32 + srow;
    const int cc   = c ^ ((rr >> 1) & 3);
    const int scol = cc * 8;

    const ushort* ag0 = A + (size_t)(m0 + rr) * lda + scol;
    const ushort* bg0 = B + (size_t)(n0 + rr) * ldb + scol;
    const ushort* ag1 = ag0 + (size_t)16 * lda;
    const ushort* bg1 = bg0 + (size_t)16 * ldb;
    ushort* la0 = As + (wave * 32) * 32;
    ushort* la1 = la0 + 16 * 32;
    ushort* lb0 = Bs + (wave * 32) * 32;
    ushort* lb1 = lb0 + 16 * 32;

    for (int kt = 0; kt < kIters; ++kt) {
        const int k0 = kt * 32;
        async_load16(ag0 + k0, la0);
        async_load16(ag1 + k0, la1);
        async_load16(bg0 + k0, lb0);
        async_load16(bg1 + k0, lb1);
        __syncthreads();
        bf16x8 aF[4], bF[4];
#pragma unroll
        for (int i = 0; i < 4; ++i) {
            const int r = wm + i * 16 + l16;
            aF[i] = *(const bf16x8*)(As + r * 32 + ((quad ^ ((r >> 1) & 3)) * 8));
        }
#pragma unroll
        for (int j = 0; j < 4; ++j) {
            const int r = wn + j * 16 + l16;
            bF[j] = *(const bf16x8*)(Bs + r * 32 + ((quad ^ ((r >> 1) & 3)) * 8));
        }
#pragma unroll
        for (int i = 0; i < 4; ++i)
#pragma unroll
            for (int j = 0; j < 4; ++j)
                acc[i][j] = __builtin_amdgcn_mfma_f32_16x16x32_bf16(aF[i], bF[j], acc[i][j], 0, 0, 0);
        __syncthreads();
    }
}

// ------------- 3-buffer ring core with counted vmcnt (T4) -----------------
// L layout: A bufs at L + buf*4096, B bufs at L + 12288 + buf*4096 (ushorts).
// Two prefetches in flight; one s_barrier per K-step; vmcnt never drained
// to 0 in steady state.
__device__ __forceinline__ void gemm128_core_ring(
    const ushort* __restrict__ A, const ushort* __restrict__ B,
    int lda, int ldb, int m0, int n0, int kIters,
    ushort* L, f32x4 acc[4][4])
{
    const int tid  = threadIdx.x;
    const int lane = tid & 63, wave = tid >> 6;
    const int wm = (wave >> 1) * 64, wn = (wave & 1) * 64;
    const int quad = lane >> 4, l16 = lane & 15;
    const int srow = lane >> 2, c = lane & 3;
    const int rr   = wave * 32 + srow;
    const int cc   = c ^ ((rr >> 1) & 3);
    const int scol = cc * 8;

    const ushort* ag0 = A + (size_t)(m0 + rr) * lda + scol;
    const ushort* bg0 = B + (size_t)(n0 + rr) * ldb + scol;
    const ushort* ag1 = ag0 + (size_t)16 * lda;
    const ushort* bg1 = bg0 + (size_t)16 * ldb;
    const int lofs = (wave * 32) * 32;

#define RING_STAGE(KT, BUF) do {                                   \
        const int _k0 = (KT) * 32;                                 \
        ushort* _la = L + (BUF) * 4096 + lofs;                     \
        ushort* _lb = L + 12288 + (BUF) * 4096 + lofs;             \
        async_load16(ag0 + _k0, _la);                              \
        async_load16(ag1 + _k0, _la + 16 * 32);                    \
        async_load16(bg0 + _k0, _lb);                              \
        async_load16(bg1 + _k0, _lb + 16 * 32);                    \
    } while (0)

    RING_STAGE(0, 0);
    if (kIters > 1) RING_STAGE(1, 1);

    int buf = 0;
    for (int kt = 0; kt < kIters; ++kt) {
        // Own P(kt) done (4 newest = P(kt+1) may stay in flight), then
        // barrier: all waves' P(kt) landed AND all waves finished reading
        // the buffer P(kt+2) will overwrite (it was read in iter kt-1).
        if (kt + 1 < kIters) {
            asm volatile("s_waitcnt vmcnt(4)" ::: "memory");
        } else {
            asm volatile("s_waitcnt vmcnt(0)" ::: "memory");
        }
        __builtin_amdgcn_s_barrier();
        asm volatile("" ::: "memory");
        if (kt + 2 < kIters) {
            int nb = buf + 2; if (nb >= 3) nb -= 3;
            RING_STAGE(kt + 2, nb);
        }
        const ushort* as = L + buf * 4096;
        const ushort* bs = L + 12288 + buf * 4096;
        bf16x8 aF[4], bF[4];
#pragma unroll
        for (int i = 0; i < 4; ++i) {
            const int r = wm + i * 16 + l16;
            aF[i] = *(const bf16x8*)(as + r * 32 + ((quad ^ ((r >> 1) & 3)) * 8));
        }
#pragma unroll
        for (int j = 0; j < 4; ++j) {
            const int r = wn + j * 16 + l16;
            bF[j] = *(const bf16x8*)(bs + r * 32 + ((quad ^ ((r >> 1) & 3)) * 8));
        }
#pragma unroll
        for (int i = 0; i < 4; ++i)
#pragma unroll
            for (int j = 0; j < 4; ++j)
                acc[i][j] = __builtin_amdgcn_mfma_f32_16x16x32_bf16(aF[i], bF[j], acc[i][j], 0, 0, 0);
        buf += 1; if (buf == 3) buf = 0;
    }
#undef RING_STAGE
}

#define ACC_INIT4(acc) \
    _Pragma("unroll") for (int i = 0; i < 4; ++i) \
    _Pragma("unroll") for (int j = 0; j < 4; ++j) \
    _Pragma("unroll") for (int r = 0; r < 4; ++r) acc[i][j][r] = 0.0f;

// QKV + RoPE, z-split. grid (64, 8, 3). Single-buffer core (5 blocks/CU).
__global__ __launch_bounds__(256) void qkv_rope_kernel(
    const ushort* __restrict__ xb, const ushort* __restrict__ wq,
    const ushort* __restrict__ wk, const ushort* __restrict__ wv,
    const float2* __restrict__ cs,
    ushort* __restrict__ Qr, ushort* __restrict__ Kr, ushort* __restrict__ VT)
{
    __shared__ __attribute__((aligned(16))) ushort As[128 * 32];
    __shared__ __attribute__((aligned(16))) ushort Bs[128 * 32];
    const int m0 = blockIdx.x * 128;
    const int n0 = blockIdx.y * 128;
    const int z  = blockIdx.z;
    const ushort* W = (z == 0) ? wq : (z == 1) ? wk : wv;

    f32x4 acc[4][4];
    ACC_INIT4(acc)
    gemm128_core_sb(xb, W, 1024, 1024, m0, n0, 32, As, Bs, acc);

    const int lane = threadIdx.x & 63, wave = threadIdx.x >> 6;
    const int wm = (wave >> 1) * 64, wn = (wave & 1) * 64;
    const int quad = lane >> 4, l16 = lane & 15;

    if (z < 2) {
        ushort* out = (z == 0) ? Qr : Kr;
#pragma unroll
        for (int j = 0; j < 4; ++j) {
            const int n = n0 + wn + j * 16 + l16;
            const int iidx = n >> 1;
            const bool odd = n & 1;
#pragma unroll
            for (int i = 0; i < 4; ++i) {
                const int mbase = m0 + wm + i * 16 + quad * 4;
                const int pos0  = mbase & 2047;
                const float2* csp = cs + (size_t)pos0 * 512 + iidx;
#pragma unroll
                for (int r = 0; r < 4; ++r) {
                    const float2 sc = csp[(size_t)r * 512]; // (cos, sin) at pos0+r
                    float v = acc[i][j][r];
                    float p = __shfl_xor(v, 1);   // partner column n^1, same row
                    float o = odd ? (v * sc.x - p * sc.y) : (v * sc.x + p * sc.y);
                    out[(size_t)(mbase + r) * 1024 + n] = f2bf(o);
                }
            }
        }
    } else {
        // V transposed: VT[b][n][pos]; 4 consecutive pos per quad -> ushort4
#pragma unroll
        for (int i = 0; i < 4; ++i) {
            const int mbase = m0 + wm + i * 16 + quad * 4;
            const int b = mbase >> 11, pos0 = mbase & 2047;
#pragma unroll
            for (int j = 0; j < 4; ++j) {
                const int n = n0 + wn + j * 16 + l16;
                ushort4 o;
                o.x = f2bf(acc[i][j][0]); o.y = f2bf(acc[i][j][1]);
                o.z = f2bf(acc[i][j][2]); o.w = f2bf(acc[i][j][3]);
                *(ushort4*)(VT + ((size_t)b * 1024 + n) * 2048 + pos0) = o;
            }
        }
    }
}

// scores: grid (16, 16, 4); lower tiles only; S fp32 scaled 1/32. Ring core.
__global__ __launch_bounds__(256) void scores_kernel(
    const ushort* __restrict__ Qr, const ushort* __restrict__ Kr,
    float* __restrict__ S)
{
    const int m0 = blockIdx.x * 128;
    const int n0 = blockIdx.y * 128;
    if (n0 > m0 + 127) return;
    const int b = blockIdx.z;
    __shared__ __attribute__((aligned(16))) ushort L[6 * 4096];  // 48 KB
    const ushort* A = Qr + (size_t)b * 2048 * 1024;
    const ushort* B = Kr + (size_t)b * 2048 * 1024;
    float* Sb = S + (size_t)b * 2048 * 2048;

    f32x4 acc[4][4];
    ACC_INIT4(acc)
    gemm128_core_ring(A, B, 1024, 1024, m0, n0, 32, L, acc);

    const int lane = threadIdx.x & 63, wave = threadIdx.x >> 6;
    const int wm = (wave >> 1) * 64, wn = (wave & 1) * 64;
    const int quad = lane >> 4, l16 = lane & 15;
#pragma unroll
    for (int i = 0; i < 4; ++i)
#pragma unroll
        for (int j = 0; j < 4; ++j) {
            const int n = n0 + wn + j * 16 + l16;
#pragma unroll
            for (int r = 0; r < 4; ++r) {
                const int m = m0 + wm + i * 16 + quad * 4 + r;
                Sb[(size_t)m * 2048 + n] = acc[i][j][r] * 0.03125f;
            }
        }
}

// Row softmax, register-staged: 8 elems/thread, one int4 bf16 write.
// Reads clipped to nvalid; writes clipped to roundup(row+1,128).
__global__ __launch_bounds__(256) void softmax_kernel(
    const float* __restrict__ S, ushort* __restrict__ P)
{
    __shared__ float red[256];
    const int row = blockIdx.x, tid = threadIdx.x, b = blockIdx.y;
    const float* s = S + ((size_t)b * 2048 + row) * 2048;
    ushort*      p = P + ((size_t)b * 2048 + row) * 2048;
    const int nvalid = row + 1;
    const int wlimit = (row & ~127) + 128;
    const int j0 = tid * 8;

    float v[8] = {0.0f, 0.0f, 0.0f, 0.0f, 0.0f, 0.0f, 0.0f, 0.0f};
    if (j0 < nvalid) {
        float4 f0 = *(const float4*)(s + j0);
        v[0]=f0.x; v[1]=f0.y; v[2]=f0.z; v[3]=f0.w;
    }
    if (j0 + 4 < nvalid) {
        float4 f1 = *(const float4*)(s + j0 + 4);
        v[4]=f1.x; v[5]=f1.y; v[6]=f1.z; v[7]=f1.w;
    }

    float mx = -3.402823466e38f;
#pragma unroll
    for (int u = 0; u < 8; ++u) if (j0 + u < nvalid) mx = fmaxf(mx, v[u]);
    red[tid] = mx; __syncthreads();
    for (int off = 128; off > 0; off >>= 1) {
        if (tid < off) red[tid] = fmaxf(red[tid], red[tid + off]);
        __syncthreads();
    }
    mx = red[0]; __syncthreads();

    float sum = 0.0f;
#pragma unroll
    for (int u = 0; u < 8; ++u) {
        v[u] = (j0 + u < nvalid) ? __expf(v[u] - mx) : 0.0f;
        sum += v[u];
    }
    red[tid] = sum; __syncthreads();
    for (int off = 128; off > 0; off >>= 1) {
        if (tid < off) red[tid] += red[tid + off];
        __syncthreads();
    }
    const float inv = 1.0f / red[0];

    if (j0 < wlimit) {
        ushort o[8];
#pragma unroll
        for (int u = 0; u < 8; ++u) o[u] = f2bf(v[u] * inv);
        *(int4*)(p + j0) = *(const int4*)o;
    }
}

// pv: grid (16, 8, 4); causal k-limit; ring core; m-tile interleave for
// K-balance (kIters 4..64 -> pair heavy with light in dispatch order).
__global__ __launch_bounds__(256) void pv_kernel(
    const ushort* __restrict__ P, const ushort* __restrict__ VT,
    float* __restrict__ out)
{
    __shared__ __attribute__((aligned(16))) ushort L[6 * 4096];  // 48 KB
    const int x  = blockIdx.x;
    const int mt = (x & 1) ? (15 - (x >> 1)) : (x >> 1);  // 0,15,1,14,...
    const int m0 = mt * 128;
    const int n0 = blockIdx.y * 128;
    const int b  = blockIdx.z;
    const ushort* A = P + (size_t)b * 2048 * 2048;
    const ushort* B = VT + (size_t)b * 1024 * 2048;
    const int kIters = (m0 + 128) / 32;   // causal: P[m][k]=0 for k>m

    f32x4 acc[4][4];
    ACC_INIT4(acc)
    gemm128_core_ring(A, B, 2048, 2048, m0, n0, kIters, L, acc);

    const int lane = threadIdx.x & 63, wave = threadIdx.x >> 6;
    const int wm = (wave >> 1) * 64, wn = (wave & 1) * 64;
    const int quad = lane >> 4, l16 = lane & 15;
#pragma unroll
    for (int i = 0; i < 4; ++i)
#pragma unroll
        for (int j = 0; j < 4; ++j) {
            const int n = n0 + wn + j * 16 + l16;
#pragma unroll
            for (int r = 0; r < 4; ++r) {
                const int m = m0 + wm + i * 16 + quad * 4 + r;
                out[((size_t)b * 2048 + m) * 1024 + n] = acc[i][j][r];
            }
        }
}

extern "C" void kernel_launch(void* const* d_in, const int* in_sizes, int n_in,
                              void* d_out, int out_size, void* d_ws, size_t ws_size,
                              hipStream_t stream) {
    const float* x  = (const float*)d_in[0];
    const float* wq = (const float*)d_in[1];
    const float* wk = (const float*)d_in[2];
    const float* wv = (const float*)d_in[3];

    const size_t MiB = 1024 * 1024;
    char* ws = (char*)d_ws;
    ushort* xb  = (ushort*)(ws);              //  16 MiB [8192][1024] bf16
    ushort* wqb = (ushort*)(ws +  16 * MiB);  //   2 MiB
    ushort* wkb = (ushort*)(ws +  18 * MiB);  //   2 MiB
    ushort* wvb = (ushort*)(ws +  20 * MiB);  //   2 MiB
    ushort* Qr  = (ushort*)(ws +  22 * MiB);  //  16 MiB [4][2048][1024] bf16
    ushort* Kr  = (ushort*)(ws +  38 * MiB);  //  16 MiB
    ushort* VT  = (ushort*)(ws +  54 * MiB);  //  16 MiB [4][1024][2048] bf16
    float*  S   = (float* )(ws +  70 * MiB);  //  64 MiB [4][2048][2048] f32
    ushort* P   = (ushort*)(ws + 134 * MiB);  //  32 MiB [4][2048][2048] bf16
    float2* cs  = (float2*)(ws + 166 * MiB);  //   8 MiB [2048][512] (cos,sin) f32
    float*  out = (float*)d_out;              // ws use: 174 MiB (256 avail)

    cvt_all_kernel <<<dim3(8192, 5),   256, 0, stream>>>(x, wq, wk, wv, xb, wqb, wkb, wvb, cs);
    qkv_rope_kernel<<<dim3(64, 8, 3),  256, 0, stream>>>(xb, wqb, wkb, wvb, cs, Qr, Kr, VT);
    scores_kernel  <<<dim3(16, 16, 4), 256, 0, stream>>>(Qr, Kr, S);
    softmax_kernel <<<dim3(2048, 4),   256, 0, stream>>>(S, P);
    pv_kernel      <<<dim3(16, 8, 4),  256, 0, stream>>>(P, VT, out);
}